// Round 1
// baseline (285.933 us; speedup 1.0000x reference)
//
#include <hip/hip_runtime.h>
#include <math.h>

#define NK 2048
#define NT 512
#define NC 32
#define NM 512

// ws layout (floats): [0..31]=v, [32..63]=u, then 6 row buffers of 512:
// r0 (eff wd3), r1, r2, r3, r4, g

__device__ __forceinline__ float eff_w(float w, float m) {
    // tanh(w) * sigmoid(m)
    return tanhf(w) * (1.0f / (1.0f + expf(-m)));
}

__global__ __launch_bounds__(256) void prep_kernel(
    const float* __restrict__ wz1, const float* __restrict__ mz1,
    const float* __restrict__ wz2, const float* __restrict__ mz2,
    const float* __restrict__ wu,  const float* __restrict__ mu,
    const float* __restrict__ wd3, const float* __restrict__ md3,
    float* __restrict__ ws)
{
    __shared__ float W1[NC * NC];
    __shared__ float W2[NC];
    const int tid = threadIdx.x;
    for (int e = tid; e < NC * NC; e += 256) W1[e] = eff_w(wz1[e], mz1[e]);
    if (tid < NC) W2[tid] = eff_w(wz2[tid], mz2[tid]);
    __syncthreads();
    if (tid < NC) {
        float acc = 0.f;
        for (int j = 0; j < NC; ++j) acc += W2[j] * W1[j * NC + tid];
        ws[tid] = acc;                               // v[c] = (W2 @ W1)[c]
        ws[32 + tid] = eff_w(wu[tid], mu[tid]);      // u[c]
    }
    // r0 = eff(wd3, md3)  (row vector, 512)
    for (int t = tid; t < NM; t += 256) ws[64 + t] = eff_w(wd3[t], md3[t]);
    // zero r1..g (atomic accumulation targets; ws is poisoned 0xAA)
    for (int e = tid; e < 5 * NM; e += 256) ws[64 + NM + e] = 0.f;
}

// rout[j] += sum_i rin[i] * eff(W[i,j]);  W is (512,512) row-major [out=i][in=j]?
// No: here W[i*512+j] with i = contraction index (row of stored matrix),
// which implements rin @ W_eff exactly as needed for the row-vector chain.
__global__ __launch_bounds__(256) void chain_kernel(
    const float* __restrict__ w, const float* __restrict__ m,
    const float* __restrict__ rin, float* __restrict__ rout)
{
    __shared__ float row[8];
    const int tid = threadIdx.x;
    const int b = blockIdx.x;           // 64 blocks, 8 contraction rows each
    if (tid < 8) row[tid] = rin[b * 8 + tid];
    __syncthreads();
    float acc0 = 0.f, acc1 = 0.f;
    const int j0 = tid, j1 = tid + 256;
    #pragma unroll
    for (int ii = 0; ii < 8; ++ii) {
        const int i = b * 8 + ii;
        const float ri = row[ii];
        const size_t off = (size_t)i * NM;
        acc0 += ri * eff_w(w[off + j0], m[off + j0]);
        acc1 += ri * eff_w(w[off + j1], m[off + j1]);
    }
    atomicAdd(&rout[j0], acc0);
    atomicAdd(&rout[j1], acc1);
}

// One block per k: delta[k] = sum_{t,c} X[k,t,c] * g[t] * v[c], then
// y[k,c] = delta*u[c] + baseline*(1 + 0.001*noise)
__global__ __launch_bounds__(256) void big_kernel(
    const float* __restrict__ X, const float* __restrict__ noise,
    const float* __restrict__ ws, float* __restrict__ out)
{
    __shared__ float gl[NT];
    __shared__ float vl[NC];
    __shared__ float ul[NC];
    __shared__ float wred[4];
    __shared__ float lastx[NC];
    const int tid = threadIdx.x;
    const int k = blockIdx.x;
    const float* __restrict__ g = ws + 64 + 5 * NM;
    for (int t = tid; t < NT; t += 256) gl[t] = g[t];
    if (tid < NC) { vl[tid] = ws[tid]; ul[tid] = ws[32 + tid]; }
    __syncthreads();

    const float4* __restrict__ Xk = (const float4*)(X + (size_t)k * (NT * NC));
    float acc = 0.f;
    #pragma unroll
    for (int it = 0; it < 16; ++it) {
        const int idx4 = tid + it * 256;       // 4096 float4 per k
        const float4 x = Xk[idx4];
        const int flat = idx4 * 4;
        const int t = flat >> 5;               // 32 floats per t-row; float4 stays in-row
        const int c = flat & 31;
        acc += gl[t] * (x.x * vl[c] + x.y * vl[c + 1] + x.z * vl[c + 2] + x.w * vl[c + 3]);
    }
    // wave64 reduce, then cross-wave via LDS
    #pragma unroll
    for (int off = 32; off > 0; off >>= 1) acc += __shfl_down(acc, off, 64);
    if ((tid & 63) == 0) wred[tid >> 6] = acc;
    if (tid < NC) lastx[tid] = X[(size_t)k * (NT * NC) + (size_t)(NT - 1) * NC + tid];
    __syncthreads();

    if (tid < NC) {
        const float delta = wred[0] + wred[1] + wred[2] + wred[3];
        float s = 0.f;
        #pragma unroll
        for (int j = 0; j < NC; ++j) s += lastx[j];
        const float bse = lastx[tid] - s * (1.0f / NC);
        const float n = noise[k * NC + tid];
        out[k * NC + tid] = delta * ul[tid] + bse * (1.0f + 0.001f * n);
    }
}

extern "C" void kernel_launch(void* const* d_in, const int* in_sizes, int n_in,
                              void* d_out, int out_size, void* d_ws, size_t ws_size,
                              hipStream_t stream)
{
    const float* X     = (const float*)d_in[0];
    const float* noise = (const float*)d_in[1];
    const float* wz1   = (const float*)d_in[2];
    const float* mz1   = (const float*)d_in[3];
    const float* wz2   = (const float*)d_in[4];
    const float* mz2   = (const float*)d_in[5];
    const float* wu    = (const float*)d_in[6];
    const float* mu    = (const float*)d_in[7];
    const float* wt1   = (const float*)d_in[8];
    const float* mt1   = (const float*)d_in[9];
    const float* wt2   = (const float*)d_in[10];
    const float* mt2   = (const float*)d_in[11];
    const float* wt3   = (const float*)d_in[12];
    const float* mt3   = (const float*)d_in[13];
    const float* wd1   = (const float*)d_in[14];
    const float* md1   = (const float*)d_in[15];
    const float* wd2   = (const float*)d_in[16];
    const float* md2   = (const float*)d_in[17];
    const float* wd3   = (const float*)d_in[18];
    const float* md3   = (const float*)d_in[19];
    float* out = (float*)d_out;
    float* ws  = (float*)d_ws;

    float* r0 = ws + 64;
    float* r1 = r0 + NM;
    float* r2 = r1 + NM;
    float* r3 = r2 + NM;
    float* r4 = r3 + NM;
    float* gv = r4 + NM;

    prep_kernel<<<1, 256, 0, stream>>>(wz1, mz1, wz2, mz2, wu, mu, wd3, md3, ws);
    // g = eff(wd3) @ eff(wd2) @ eff(wd1) @ eff(wt3) @ eff(wt2) @ eff(wt1)
    chain_kernel<<<64, 256, 0, stream>>>(wd2, md2, r0, r1);
    chain_kernel<<<64, 256, 0, stream>>>(wd1, md1, r1, r2);
    chain_kernel<<<64, 256, 0, stream>>>(wt3, mt3, r2, r3);
    chain_kernel<<<64, 256, 0, stream>>>(wt2, mt2, r3, r4);
    chain_kernel<<<64, 256, 0, stream>>>(wt1, mt1, r4, gv);
    big_kernel<<<NK, 256, 0, stream>>>(X, noise, ws, out);
}